// Round 2
// baseline (3061.240 us; speedup 1.0000x reference)
//
#include <hip/hip_runtime.h>
#include <hip/hip_bf16.h>
#include <math.h>

#define N_NODES 100000
#define N_EDGES 500000
#define MEM 128
#define IN_DIM 256
#define EDGEF 64
#define D_EDGE 128
#define EPSILON 0.1f
#define GAMMA 0.1f
#define SCALE 0.08838834764831845f  // 1/sqrt(128)

#define NPB 8     // nodes per block in k_node_proj
#define T_TILE 8  // edges per tile in k_agg_fused

__global__ void k_prepA(const float* __restrict__ W_anti, float* __restrict__ Abuf) {
    int idx = blockIdx.x * blockDim.x + threadIdx.x;  // 16384 total
    int m = idx >> 7, d = idx & 127;
    float a = W_anti[m * 128 + d] - W_anti[d * 128 + m];
    if (m == d) a -= GAMMA;
    Abuf[idx] = a;
}

// h = x@W_enc^T + b_enc ; q,k,v = h@W^T + b  (fused, NPB nodes per block)
__global__ __launch_bounds__(128) void k_node_proj(
    const float* __restrict__ x,
    const float* __restrict__ W_enc, const float* __restrict__ b_enc,
    const float* __restrict__ Wq, const float* __restrict__ bq,
    const float* __restrict__ Wk, const float* __restrict__ bk,
    const float* __restrict__ Wv, const float* __restrict__ bv,
    float* __restrict__ h, float* __restrict__ q,
    float* __restrict__ k, float* __restrict__ v)
{
    __shared__ float xs[NPB][IN_DIM];
    __shared__ float hs[NPB][MEM];
    const int m = threadIdx.x;       // 0..127 output dim
    const int n0 = blockIdx.x * NPB;

    for (int j = 0; j < NPB; j++) {
        const float* xr = x + (size_t)(n0 + j) * IN_DIM;
        xs[j][m] = xr[m];
        xs[j][m + 128] = xr[m + 128];
    }
    __syncthreads();

    float acc[NPB];
    float be = b_enc[m];
    for (int j = 0; j < NPB; j++) acc[j] = be;
    const float4* W4 = (const float4*)(W_enc + (size_t)m * IN_DIM);
    for (int d4 = 0; d4 < IN_DIM / 4; d4++) {
        float4 w = W4[d4];
        int d = d4 * 4;
        for (int j = 0; j < NPB; j++)
            acc[j] += w.x * xs[j][d] + w.y * xs[j][d + 1] + w.z * xs[j][d + 2] + w.w * xs[j][d + 3];
    }
    for (int j = 0; j < NPB; j++) {
        h[(size_t)(n0 + j) * MEM + m] = acc[j];
        hs[j][m] = acc[j];
    }
    __syncthreads();

#define PROJ(W, B, OUT)                                                          \
    {                                                                            \
        float a2[NPB];                                                           \
        float bb = B[m];                                                         \
        for (int j = 0; j < NPB; j++) a2[j] = bb;                                \
        const float4* Wb = (const float4*)(W + (size_t)m * MEM);                 \
        for (int d4 = 0; d4 < MEM / 4; d4++) {                                   \
            float4 w = Wb[d4];                                                   \
            int d = d4 * 4;                                                      \
            for (int j = 0; j < NPB; j++)                                        \
                a2[j] += w.x * hs[j][d] + w.y * hs[j][d + 1] + w.z * hs[j][d + 2] \
                       + w.w * hs[j][d + 3];                                     \
        }                                                                        \
        for (int j = 0; j < NPB; j++) OUT[(size_t)(n0 + j) * MEM + m] = a2[j];   \
    }
    PROJ(Wq, bq, q)
    PROJ(Wk, bk, k)
    PROJ(Wv, bv, v)
#undef PROJ
}

__global__ void k_hist(const int* __restrict__ ei, int* __restrict__ cnt) {
    int i = blockIdx.x * blockDim.x + threadIdx.x;
    if (i < N_EDGES) atomicAdd(&cnt[ei[N_EDGES + i]], 1);
}

// single-block exclusive scan of cnt[0..N) -> offsets[0..N], cursor copy
__global__ __launch_bounds__(1024) void k_scan(
    const int* __restrict__ cnt, int* __restrict__ offsets, int* __restrict__ cursor)
{
    __shared__ int buf[2][1024];
    const int tid = threadIdx.x;
    int base = 0;
    for (int c0 = 0; c0 < N_NODES; c0 += 1024) {
        int i = c0 + tid;
        int val = (i < N_NODES) ? cnt[i] : 0;
        buf[0][tid] = val;
        __syncthreads();
        int src = 0;
        for (int off = 1; off < 1024; off <<= 1) {
            int xv = buf[src][tid];
            if (tid >= off) xv += buf[src][tid - off];
            buf[1 - src][tid] = xv;
            __syncthreads();
            src = 1 - src;
        }
        int incl = buf[src][tid];
        int tot = buf[src][1023];
        int excl = incl - val;
        if (i < N_NODES) {
            offsets[i] = base + excl;
            cursor[i] = base + excl;
        }
        __syncthreads();  // protect buf before next chunk overwrites
        base += tot;
    }
    if (tid == 0) offsets[N_NODES] = base;
}

__global__ void k_scatter(const int* __restrict__ ei, int* __restrict__ cursor,
                          int* __restrict__ perm) {
    int i = blockIdx.x * blockDim.x + threadIdx.x;
    if (i < N_EDGES) {
        int d = ei[N_EDGES + i];
        int pos = atomicAdd(&cursor[d], 1);
        perm[pos] = i;
    }
}

// One block (128 threads) per destination node. Online-softmax over its edges,
// fused with the antisymmetric update epilogue.
__global__ __launch_bounds__(128) void k_agg_fused(
    const int* __restrict__ ei, const float* __restrict__ last_update,
    const float* __restrict__ t, const float* __restrict__ msg,
    const float* __restrict__ w_time, const float* __restrict__ b_time,
    const float* __restrict__ We,
    const float* __restrict__ q, const float* __restrict__ k,
    const float* __restrict__ v, const float* __restrict__ h,
    const float* __restrict__ Abuf, const float* __restrict__ b_anti,
    const int* __restrict__ offsets, const int* __restrict__ perm,
    float* __restrict__ out)
{
    const int n = blockIdx.x;
    const int m = threadIdx.x;
    const int lane = m & 63, wv = m >> 6;

    __shared__ float ea[T_TILE][D_EDGE];
    __shared__ float ep_lds[T_TILE][MEM];
    __shared__ int s_src[T_TILE];
    __shared__ int s_eid[T_TILE];
    __shared__ float s_rel[T_TILE];
    __shared__ float red[T_TILE][2];
    __shared__ float hsh[MEM];

    const int off0 = offsets[n];
    const int deg = offsets[n + 1] - off0;

    const float qm = q[(size_t)n * MEM + m];
    float accm = 0.f;
    float maxv = -INFINITY;
    float denom = 0.f;

    float wt = 0.f, bt = 0.f;
    if (m >= 64) { wt = w_time[m - 64]; bt = b_time[m - 64]; }

    const float4* We4 = (const float4*)(We + (size_t)m * D_EDGE);

    for (int base = 0; base < deg; base += T_TILE) {
        const int cnt = min(T_TILE, deg - base);
        __syncthreads();
        if (m < cnt) {
            int e = perm[off0 + base + m];
            int sn = ei[e];
            s_eid[m] = e;
            s_src[m] = sn;
            s_rel[m] = fabsf(last_update[sn] - t[e]);
        }
        __syncthreads();
        for (int j = 0; j < cnt; j++) {
            float val;
            if (m < 64) val = msg[(size_t)s_eid[j] * EDGEF + m];
            else        val = cosf(s_rel[j] * wt + bt);
            ea[j][m] = val;
        }
        __syncthreads();
        for (int j = 0; j < cnt; j++) {
            const float4* ea4 = (const float4*)ea[j];
            float s0 = 0.f, s1 = 0.f, s2 = 0.f, s3 = 0.f;
#pragma unroll
            for (int d4 = 0; d4 < D_EDGE / 4; d4 += 4) {
                float4 w0 = We4[d4],     a0 = ea4[d4];
                float4 w1 = We4[d4 + 1], a1 = ea4[d4 + 1];
                float4 w2 = We4[d4 + 2], a2 = ea4[d4 + 2];
                float4 w3 = We4[d4 + 3], a3 = ea4[d4 + 3];
                s0 += w0.x * a0.x + w0.y * a0.y + w0.z * a0.z + w0.w * a0.w;
                s1 += w1.x * a1.x + w1.y * a1.y + w1.z * a1.z + w1.w * a1.w;
                s2 += w2.x * a2.x + w2.y * a2.y + w2.z * a2.z + w2.w * a2.w;
                s3 += w3.x * a3.x + w3.y * a3.y + w3.z * a3.z + w3.w * a3.w;
            }
            float epj = (s0 + s1) + (s2 + s3);
            ep_lds[j][m] = epj;
            float kge = k[(size_t)s_src[j] * MEM + m] + epj;
            float p = qm * kge;
            for (int off = 32; off > 0; off >>= 1) p += __shfl_down(p, off, 64);
            if (lane == 0) red[j][wv] = p;
        }
        __syncthreads();
        // softmax update — uniform (all values from LDS broadcast)
        float tmax = maxv;
        for (int j = 0; j < cnt; j++)
            tmax = fmaxf(tmax, (red[j][0] + red[j][1]) * SCALE);
        float rescale = expf(maxv - tmax);  // maxv=-inf first tile -> 0
        accm *= rescale;
        denom *= rescale;
        for (int j = 0; j < cnt; j++) {
            float aj = (red[j][0] + red[j][1]) * SCALE;
            float ex = expf(aj - tmax);
            denom += ex;
            float ve = v[(size_t)s_src[j] * MEM + m] + ep_lds[j][m];
            accm += ex * ve;
        }
        maxv = tmax;
    }

    // epilogue: g = h@A^T + attn + b_anti; out = tanh(h + eps*tanh(g))
    __syncthreads();
    hsh[m] = h[(size_t)n * MEM + m];
    __syncthreads();
    float attn = accm / (denom + 1e-16f);  // deg==0 -> 0
    float g = b_anti[m] + attn;
    const float4* A4 = (const float4*)(Abuf + (size_t)m * MEM);
    const float4* h4 = (const float4*)hsh;
    float g0 = 0.f, g1 = 0.f;
#pragma unroll
    for (int d4 = 0; d4 < MEM / 4; d4 += 2) {
        float4 w0 = A4[d4],     x0 = h4[d4];
        float4 w1 = A4[d4 + 1], x1 = h4[d4 + 1];
        g0 += w0.x * x0.x + w0.y * x0.y + w0.z * x0.z + w0.w * x0.w;
        g1 += w1.x * x1.x + w1.y * x1.y + w1.z * x1.z + w1.w * x1.w;
    }
    g += g0 + g1;
    float hv = hsh[m] + EPSILON * tanhf(g);
    out[(size_t)n * MEM + m] = tanhf(hv);
}

extern "C" void kernel_launch(void* const* d_in, const int* in_sizes, int n_in,
                              void* d_out, int out_size, void* d_ws, size_t ws_size,
                              hipStream_t stream) {
    const float* x          = (const float*)d_in[0];
    const float* last_update= (const float*)d_in[1];
    const int*   ei         = (const int*)  d_in[2];
    const float* t          = (const float*)d_in[3];
    const float* msg        = (const float*)d_in[4];
    const float* w_time     = (const float*)d_in[5];
    const float* b_time     = (const float*)d_in[6];
    const float* W_enc      = (const float*)d_in[7];
    const float* b_enc      = (const float*)d_in[8];
    const float* Wq         = (const float*)d_in[9];
    const float* bq         = (const float*)d_in[10];
    const float* Wk         = (const float*)d_in[11];
    const float* bk         = (const float*)d_in[12];
    const float* Wv         = (const float*)d_in[13];
    const float* bv         = (const float*)d_in[14];
    const float* We         = (const float*)d_in[15];
    const float* W_anti     = (const float*)d_in[16];
    const float* b_anti     = (const float*)d_in[17];
    float* out = (float*)d_out;

    // workspace layout (floats)
    float* ws = (float*)d_ws;
    size_t nm = (size_t)N_NODES * MEM;
    float* h    = ws;            // N*128
    float* q    = h + nm;        // N*128
    float* k    = q + nm;        // N*128
    float* v    = k + nm;        // N*128
    float* Abuf = v + nm;        // 128*128
    int* cnt     = (int*)(Abuf + MEM * MEM);  // N
    int* offsets = cnt + N_NODES;             // N+1
    int* cursor  = offsets + N_NODES + 1;     // N
    int* perm    = cursor + N_NODES;          // E

    hipMemsetAsync(cnt, 0, N_NODES * sizeof(int), stream);
    k_prepA<<<(MEM * MEM) / 256, 256, 0, stream>>>(W_anti, Abuf);

    k_node_proj<<<N_NODES / NPB, 128, 0, stream>>>(
        x, W_enc, b_enc, Wq, bq, Wk, bk, Wv, bv, h, q, k, v);

    k_hist<<<(N_EDGES + 255) / 256, 256, 0, stream>>>(ei, cnt);
    k_scan<<<1, 1024, 0, stream>>>(cnt, offsets, cursor);
    k_scatter<<<(N_EDGES + 255) / 256, 256, 0, stream>>>(ei, cursor, perm);

    k_agg_fused<<<N_NODES, 128, 0, stream>>>(
        ei, last_update, t, msg, w_time, b_time, We,
        q, k, v, h, Abuf, b_anti, offsets, perm, out);
}

// Round 3
// 1423.353 us; speedup vs baseline: 2.1507x; 2.1507x over previous
//
#include <hip/hip_runtime.h>
#include <hip/hip_bf16.h>
#include <math.h>

#define N_NODES 100000
#define N_EDGES 500000
#define MEM 128
#define IN_DIM 256
#define EDGEF 64
#define D_EDGE 128
#define EPSILON 0.1f
#define GAMMA 0.1f
#define SCALE 0.08838834764831845f  // 1/sqrt(128)

#define NPB 8     // nodes per block in k_node_proj / k_final
#define ET 32     // edges per block in k_edge_all (500000/32 = 15625)
#define EA_LD 136 // padded LDS row for bf16 tiles (+8 keeps 16B align, kills conflicts)
#define EP_LD 132 // padded LDS row for fp32 ep tile

typedef __attribute__((ext_vector_type(8))) short bf16x8;
typedef __attribute__((ext_vector_type(4))) float f32x4;

__device__ __forceinline__ short f2bs(float f) {
    __hip_bfloat16 b = __float2bfloat16(f);
    return *(short*)&b;
}

// Abuf = W_anti - W_anti^T - gamma*I ; Web = bf16(We)
__global__ void k_prep(const float* __restrict__ W_anti, const float* __restrict__ We,
                       float* __restrict__ Abuf, unsigned short* __restrict__ Web) {
    int idx = blockIdx.x * blockDim.x + threadIdx.x;  // 16384
    int m = idx >> 7, d = idx & 127;
    float a = W_anti[m * 128 + d] - W_anti[d * 128 + m];
    if (m == d) a -= GAMMA;
    Abuf[idx] = a;
    Web[idx] = (unsigned short)f2bs(We[idx]);
}

// h = x@W_enc^T + b_enc ; q,k,v = h@W^T + b  (fused, NPB nodes per block)
__global__ __launch_bounds__(128) void k_node_proj(
    const float* __restrict__ x,
    const float* __restrict__ W_enc, const float* __restrict__ b_enc,
    const float* __restrict__ Wq, const float* __restrict__ bq,
    const float* __restrict__ Wk, const float* __restrict__ bk,
    const float* __restrict__ Wv, const float* __restrict__ bv,
    float* __restrict__ h, float* __restrict__ q,
    float* __restrict__ k, float* __restrict__ v)
{
    __shared__ float xs[NPB][IN_DIM];
    __shared__ float hs[NPB][MEM];
    const int m = threadIdx.x;
    const int n0 = blockIdx.x * NPB;

    for (int j = 0; j < NPB; j++) {
        const float* xr = x + (size_t)(n0 + j) * IN_DIM;
        xs[j][m] = xr[m];
        xs[j][m + 128] = xr[m + 128];
    }
    __syncthreads();

    float acc[NPB];
    float be = b_enc[m];
    for (int j = 0; j < NPB; j++) acc[j] = be;
    const float4* W4 = (const float4*)(W_enc + (size_t)m * IN_DIM);
    for (int d4 = 0; d4 < IN_DIM / 4; d4++) {
        float4 w = W4[d4];
        int d = d4 * 4;
        for (int j = 0; j < NPB; j++)
            acc[j] += w.x * xs[j][d] + w.y * xs[j][d + 1] + w.z * xs[j][d + 2] + w.w * xs[j][d + 3];
    }
    for (int j = 0; j < NPB; j++) {
        h[(size_t)(n0 + j) * MEM + m] = acc[j];
        hs[j][m] = acc[j];
    }
    __syncthreads();

#define PROJ(W, B, OUT)                                                          \
    {                                                                            \
        float a2[NPB];                                                           \
        float bb = B[m];                                                         \
        for (int j = 0; j < NPB; j++) a2[j] = bb;                                \
        const float4* Wb = (const float4*)(W + (size_t)m * MEM);                 \
        for (int d4 = 0; d4 < MEM / 4; d4++) {                                   \
            float4 w = Wb[d4];                                                   \
            int d = d4 * 4;                                                      \
            for (int j = 0; j < NPB; j++)                                        \
                a2[j] += w.x * hs[j][d] + w.y * hs[j][d + 1] + w.z * hs[j][d + 2] \
                       + w.w * hs[j][d + 3];                                     \
        }                                                                        \
        for (int j = 0; j < NPB; j++) OUT[(size_t)(n0 + j) * MEM + m] = a2[j];   \
    }
    PROJ(Wq, bq, q)
    PROJ(Wk, bk, k)
    PROJ(Wv, bv, v)
#undef PROJ
}

// One pass over edges: build edge_attr (bf16), e_proj via MFMA (fp32 in LDS),
// alpha = q.(k+ep)*scale, ex = exp(alpha) [no max-shift: |alpha| small, softmax
// is shift-invariant], atomicAdd into agg/denom.
__global__ __launch_bounds__(256) void k_edge_all(
    const int* __restrict__ ei, const float* __restrict__ last_update,
    const float* __restrict__ t, const float* __restrict__ msg,
    const float* __restrict__ w_time, const float* __restrict__ b_time,
    const unsigned short* __restrict__ Web,
    const float* __restrict__ q, const float* __restrict__ k,
    const float* __restrict__ v,
    float* __restrict__ agg, float* __restrict__ denom)
{
    __shared__ short sWe[128][EA_LD];                       // 34.8 KB
    __shared__ __align__(16) char ubuf[ET * EP_LD * 4];     // 16.9 KB (EA then EP)
    short (*sEA)[EA_LD] = (short (*)[EA_LD])ubuf;
    float (*sEP)[EP_LD] = (float (*)[EP_LD])ubuf;
    __shared__ int s_src[ET], s_dst[ET];
    __shared__ float s_rel[ET];
    __shared__ float red[2][2][2];

    const int tid = threadIdx.x;
    const size_t e0 = (size_t)blockIdx.x * ET;

    // stage We (bf16) into LDS: thread -> row tid>>1, 64-col half
    {
        int r = tid >> 1, c0 = (tid & 1) * 64;
        const uint4* s = (const uint4*)(Web + r * 128 + c0);
        uint4* d = (uint4*)&sWe[r][c0];
#pragma unroll
        for (int i = 0; i < 8; i++) d[i] = s[i];
    }
    if (tid < ET) {
        size_t e = e0 + tid;
        int sn = ei[e];
        s_src[tid] = sn;
        s_dst[tid] = ei[N_EDGES + e];
        s_rel[tid] = fabsf(last_update[sn] - t[e]);
    }
    __syncthreads();

    // stage EA tile (32 edges x 128) as bf16: j = edge, seg = 16-col chunk
    {
        int j = tid >> 3, seg = tid & 7, k0 = seg * 16;
        size_t e = e0 + j;
        float vals[16];
        if (seg < 4) {
            const float4* mp = (const float4*)(msg + e * EDGEF + k0);
#pragma unroll
            for (int i = 0; i < 4; i++) {
                float4 a = mp[i];
                vals[4 * i] = a.x; vals[4 * i + 1] = a.y;
                vals[4 * i + 2] = a.z; vals[4 * i + 3] = a.w;
            }
        } else {
            int td = k0 - 64;
            float rel = s_rel[j];
#pragma unroll
            for (int i = 0; i < 16; i++)
                vals[i] = cosf(rel * w_time[td + i] + b_time[td + i]);
        }
        unsigned int* dp = (unsigned int*)&sEA[j][k0];
#pragma unroll
        for (int i = 0; i < 8; i++) {
            unsigned int lo = (unsigned short)f2bs(vals[2 * i]);
            unsigned int hi = (unsigned short)f2bs(vals[2 * i + 1]);
            dp[i] = lo | (hi << 16);
        }
    }
    __syncthreads();

    // MFMA: ep(32x128) = EA(32x128) @ We^T. wave -> (mt, 4 n-tiles)
    const int wave = tid >> 6, lane = tid & 63;
    const int quad = lane >> 4, l16 = lane & 15;
    const int mt = wave & 1, ntb = (wave >> 1) * 4;
    f32x4 acc[4];
#pragma unroll
    for (int i = 0; i < 4; i++) acc[i] = (f32x4){0.f, 0.f, 0.f, 0.f};
#pragma unroll
    for (int ko = 0; ko < 4; ko++) {
        bf16x8 a = *(const bf16x8*)&sEA[mt * 16 + l16][ko * 32 + quad * 8];
#pragma unroll
        for (int i = 0; i < 4; i++) {
            bf16x8 b = *(const bf16x8*)&sWe[(ntb + i) * 16 + l16][ko * 32 + quad * 8];
            acc[i] = __builtin_amdgcn_mfma_f32_16x16x32_bf16(a, b, acc[i], 0, 0, 0);
        }
    }
    __syncthreads();  // sEA dead -> reuse region as sEP
#pragma unroll
    for (int i = 0; i < 4; i++)
#pragma unroll
        for (int r = 0; r < 4; r++)
            sEP[mt * 16 + quad * 4 + r][(ntb + i) * 16 + l16] = acc[i][r];
    __syncthreads();

    // phase 2: 2 edges in flight (128 threads each)
    const int sub = tid >> 7, m = tid & 127;
    const int wv = (tid >> 6) & 1;
    for (int jj = 0; jj < ET / 2; jj++) {
        int j = jj * 2 + sub;
        int sn = s_src[j], dn = s_dst[j];
        float epv = sEP[j][m];
        float kk = k[(size_t)sn * MEM + m] + epv;
        float p = q[(size_t)dn * MEM + m] * kk;
        for (int off = 32; off > 0; off >>= 1) p += __shfl_down(p, off, 64);
        if (lane == 0) red[jj & 1][sub][wv] = p;
        __syncthreads();  // parity buffer -> one barrier per iter is safe
        float ex = expf((red[jj & 1][sub][0] + red[jj & 1][sub][1]) * SCALE);
        float vv = v[(size_t)sn * MEM + m] + epv;
        atomicAdd(&agg[(size_t)dn * MEM + m], ex * vv);
        if (m == 0) atomicAdd(&denom[dn], ex);
    }
}

__global__ __launch_bounds__(128) void k_final(
    const float* __restrict__ h, const float* __restrict__ agg,
    const float* __restrict__ denom, const float* __restrict__ Abuf,
    const float* __restrict__ b_anti, float* __restrict__ out)
{
    __shared__ float hsh[NPB][MEM];
    const int m = threadIdx.x;
    const int n0 = blockIdx.x * NPB;
    for (int j = 0; j < NPB; j++) hsh[j][m] = h[(size_t)(n0 + j) * MEM + m];
    __syncthreads();
    float acc[NPB];
    float ba = b_anti[m];
    for (int j = 0; j < NPB; j++) {
        float dn = denom[n0 + j] + 1e-16f;
        acc[j] = ba + agg[(size_t)(n0 + j) * MEM + m] / dn;
    }
    const float4* A4 = (const float4*)(Abuf + (size_t)m * MEM);
    for (int d4 = 0; d4 < MEM / 4; d4++) {
        float4 w = A4[d4];
        int d = d4 * 4;
        for (int j = 0; j < NPB; j++)
            acc[j] += w.x * hsh[j][d] + w.y * hsh[j][d + 1] + w.z * hsh[j][d + 2] + w.w * hsh[j][d + 3];
    }
    for (int j = 0; j < NPB; j++) {
        float hv = hsh[j][m] + EPSILON * tanhf(acc[j]);
        out[(size_t)(n0 + j) * MEM + m] = tanhf(hv);
    }
}

extern "C" void kernel_launch(void* const* d_in, const int* in_sizes, int n_in,
                              void* d_out, int out_size, void* d_ws, size_t ws_size,
                              hipStream_t stream) {
    const float* x          = (const float*)d_in[0];
    const float* last_update= (const float*)d_in[1];
    const int*   ei         = (const int*)  d_in[2];
    const float* t          = (const float*)d_in[3];
    const float* msg        = (const float*)d_in[4];
    const float* w_time     = (const float*)d_in[5];
    const float* b_time     = (const float*)d_in[6];
    const float* W_enc      = (const float*)d_in[7];
    const float* b_enc      = (const float*)d_in[8];
    const float* Wq         = (const float*)d_in[9];
    const float* bq         = (const float*)d_in[10];
    const float* Wk         = (const float*)d_in[11];
    const float* bk         = (const float*)d_in[12];
    const float* Wv         = (const float*)d_in[13];
    const float* bv         = (const float*)d_in[14];
    const float* We         = (const float*)d_in[15];
    const float* W_anti     = (const float*)d_in[16];
    const float* b_anti     = (const float*)d_in[17];
    float* out = (float*)d_out;

    float* ws = (float*)d_ws;
    size_t nm = (size_t)N_NODES * MEM;
    float* h     = ws;                 // N*128
    float* q     = h + nm;             // N*128
    float* k     = q + nm;             // N*128
    float* v     = k + nm;             // N*128
    float* agg   = v + nm;             // N*128
    float* denom = agg + nm;           // N   (contiguous with agg for one memset)
    float* Abuf  = denom + N_NODES;    // 128*128
    unsigned short* Web = (unsigned short*)(Abuf + MEM * MEM);  // 128*128 bf16

    hipMemsetAsync(agg, 0, (nm + N_NODES) * sizeof(float), stream);
    k_prep<<<(MEM * MEM) / 256, 256, 0, stream>>>(W_anti, We, Abuf, Web);

    k_node_proj<<<N_NODES / NPB, 128, 0, stream>>>(
        x, W_enc, b_enc, Wq, bq, Wk, bk, Wv, bv, h, q, k, v);

    k_edge_all<<<N_EDGES / ET, 256, 0, stream>>>(
        ei, last_update, t, msg, w_time, b_time, Web, q, k, v, agg, denom);

    k_final<<<N_NODES / NPB, 128, 0, stream>>>(h, agg, denom, Abuf, b_anti, out);
}

// Round 4
// 1112.242 us; speedup vs baseline: 2.7523x; 1.2797x over previous
//
#include <hip/hip_runtime.h>
#include <hip/hip_bf16.h>
#include <math.h>

#define N_NODES 100000
#define N_EDGES 500000
#define MEM 128
#define IN_DIM 256
#define EDGEF 64
#define D_EDGE 128
#define EPSILON 0.1f
#define GAMMA 0.1f
#define SCALE 0.08838834764831845f  // 1/sqrt(128)

#define NPB 8     // nodes per block in k_final
#define NT 32     // nodes per block in k_node_proj (100000/32 = 3125)
#define XP 264    // padded LDS row for x bf16 tile (shorts)
#define HP 136    // padded LDS row for h bf16 tile (shorts)
#define ET 32     // edges per block in k_edge_all
#define EA_LD 136 // padded LDS row for bf16 edge tiles
#define EP_LD 132 // padded LDS row for fp32 ep tile

typedef __attribute__((ext_vector_type(8))) short bf16x8;
typedef __attribute__((ext_vector_type(4))) float f32x4;

__device__ __forceinline__ short f2bs(float f) {
    __hip_bfloat16 b = __float2bfloat16(f);
    return *(short*)&b;
}
__device__ __forceinline__ float bs2f(short s) {
    __hip_bfloat16 b = *(__hip_bfloat16*)&s;
    return __bfloat162float(b);
}

// Abuf = W_anti - W_anti^T - gamma*I; bf16 copies of We, Wq, Wk, Wv;
// hi/lo bf16 split of W_enc.
__global__ void k_prep(const float* __restrict__ W_anti, const float* __restrict__ We,
                       const float* __restrict__ W_enc,
                       const float* __restrict__ Wq, const float* __restrict__ Wk,
                       const float* __restrict__ Wv,
                       float* __restrict__ Abuf, unsigned short* __restrict__ Web,
                       unsigned short* __restrict__ WencH, unsigned short* __restrict__ WencL,
                       unsigned short* __restrict__ Wqb, unsigned short* __restrict__ Wkb,
                       unsigned short* __restrict__ Wvb) {
    int idx = blockIdx.x * blockDim.x + threadIdx.x;  // 0..32767
    float w = W_enc[idx];
    short hi = f2bs(w);
    WencH[idx] = (unsigned short)hi;
    WencL[idx] = (unsigned short)f2bs(w - bs2f(hi));
    if (idx < 16384) {
        int m = idx >> 7, d = idx & 127;
        float a = W_anti[m * 128 + d] - W_anti[d * 128 + m];
        if (m == d) a -= GAMMA;
        Abuf[idx] = a;
        Web[idx] = (unsigned short)f2bs(We[idx]);
        Wqb[idx] = (unsigned short)f2bs(Wq[idx]);
        Wkb[idx] = (unsigned short)f2bs(Wk[idx]);
        Wvb[idx] = (unsigned short)f2bs(Wv[idx]);
    }
}

// MFMA node projections. h = x@W_enc^T + b_enc via split-precision bf16
// (x_hi*W_hi + x_lo*W_hi + x_hi*W_lo ~ fp32 accuracy — h feeds out undamped).
// q,k,v = h@W^T + b via plain bf16 (errors damped by eps*tanh downstream).
__global__ __launch_bounds__(256) void k_node_proj(
    const float* __restrict__ x,
    const float* __restrict__ b_enc, const float* __restrict__ bq,
    const float* __restrict__ bk, const float* __restrict__ bv,
    const unsigned short* __restrict__ WencH, const unsigned short* __restrict__ WencL,
    const unsigned short* __restrict__ Wqb, const unsigned short* __restrict__ Wkb,
    const unsigned short* __restrict__ Wvb,
    float* __restrict__ h, float* __restrict__ q,
    float* __restrict__ k, float* __restrict__ v)
{
    __shared__ short xhi[NT][XP];
    __shared__ short xlo[NT][XP];
    __shared__ short hb[NT][HP];
    const int tid = threadIdx.x;
    const int n0 = blockIdx.x * NT;

    // stage x tile -> hi/lo bf16 LDS
    {
        int r = tid >> 3, seg = tid & 7;  // 32 rows x 8 segs of 32 cols
        const float4* xp = (const float4*)(x + (size_t)(n0 + r) * IN_DIM + seg * 32);
        unsigned int* dh = (unsigned int*)&xhi[r][seg * 32];
        unsigned int* dl = (unsigned int*)&xlo[r][seg * 32];
#pragma unroll
        for (int i = 0; i < 8; i++) {
            float4 a = xp[i];
            float fs[4] = {a.x, a.y, a.z, a.w};
            unsigned short h2[4], l2[4];
#pragma unroll
            for (int j = 0; j < 4; j++) {
                short hbit = f2bs(fs[j]);
                h2[j] = (unsigned short)hbit;
                l2[j] = (unsigned short)f2bs(fs[j] - bs2f(hbit));
            }
            dh[2 * i]     = h2[0] | ((unsigned int)h2[1] << 16);
            dh[2 * i + 1] = h2[2] | ((unsigned int)h2[3] << 16);
            dl[2 * i]     = l2[0] | ((unsigned int)l2[1] << 16);
            dl[2 * i + 1] = l2[2] | ((unsigned int)l2[3] << 16);
        }
    }
    __syncthreads();

    const int wave = tid >> 6, lane = tid & 63;
    const int quad = lane >> 4, l16 = lane & 15;
    const int mt = wave & 1;       // 16-node half
    const int nh = wave >> 1;      // 64-col half

    // h: 3-term split-precision MFMA over K=256
    f32x4 acc[4];
#pragma unroll
    for (int i = 0; i < 4; i++) acc[i] = (f32x4){0.f, 0.f, 0.f, 0.f};
#pragma unroll
    for (int ko = 0; ko < 8; ko++) {
        bf16x8 ah = *(const bf16x8*)&xhi[mt * 16 + l16][ko * 32 + quad * 8];
        bf16x8 al = *(const bf16x8*)&xlo[mt * 16 + l16][ko * 32 + quad * 8];
#pragma unroll
        for (int i = 0; i < 4; i++) {
            size_t boff = (size_t)(nh * 64 + i * 16 + l16) * IN_DIM + ko * 32 + quad * 8;
            bf16x8 bh = *(const bf16x8*)(WencH + boff);
            bf16x8 bl = *(const bf16x8*)(WencL + boff);
            acc[i] = __builtin_amdgcn_mfma_f32_16x16x32_bf16(ah, bh, acc[i], 0, 0, 0);
            acc[i] = __builtin_amdgcn_mfma_f32_16x16x32_bf16(al, bh, acc[i], 0, 0, 0);
            acc[i] = __builtin_amdgcn_mfma_f32_16x16x32_bf16(ah, bl, acc[i], 0, 0, 0);
        }
    }
#pragma unroll
    for (int i = 0; i < 4; i++) {
        int col = nh * 64 + i * 16 + l16;
        float be = b_enc[col];
#pragma unroll
        for (int r = 0; r < 4; r++) {
            int row = mt * 16 + quad * 4 + r;
            float hv = acc[i][r] + be;
            h[(size_t)(n0 + row) * MEM + col] = hv;
            hb[row][col] = f2bs(hv);
        }
    }
    __syncthreads();

#define QKV(Wb, BIAS, OUT)                                                        \
    {                                                                             \
        f32x4 a2[4];                                                              \
        for (int i = 0; i < 4; i++) a2[i] = (f32x4){0.f, 0.f, 0.f, 0.f};          \
        for (int ko = 0; ko < 4; ko++) {                                          \
            bf16x8 a = *(const bf16x8*)&hb[mt * 16 + l16][ko * 32 + quad * 8];    \
            for (int i = 0; i < 4; i++) {                                         \
                size_t boff = (size_t)(nh * 64 + i * 16 + l16) * MEM              \
                            + ko * 32 + quad * 8;                                 \
                bf16x8 b = *(const bf16x8*)(Wb + boff);                           \
                a2[i] = __builtin_amdgcn_mfma_f32_16x16x32_bf16(a, b, a2[i], 0, 0, 0); \
            }                                                                     \
        }                                                                         \
        for (int i = 0; i < 4; i++) {                                             \
            int col = nh * 64 + i * 16 + l16;                                     \
            float bb = BIAS[col];                                                 \
            for (int r = 0; r < 4; r++) {                                         \
                int row = mt * 16 + quad * 4 + r;                                 \
                OUT[(size_t)(n0 + row) * MEM + col] = a2[i][r] + bb;              \
            }                                                                     \
        }                                                                         \
    }
    QKV(Wqb, bq, q)
    QKV(Wkb, bk, k)
    QKV(Wvb, bv, v)
#undef QKV
}

// One pass over edges: build edge_attr (bf16), e_proj via MFMA (fp32 in LDS),
// alpha = q.(k+ep)*scale, ex = exp(alpha) [no max-shift: |alpha| small, softmax
// is shift-invariant], atomicAdd into agg/denom.
__global__ __launch_bounds__(256) void k_edge_all(
    const int* __restrict__ ei, const float* __restrict__ last_update,
    const float* __restrict__ t, const float* __restrict__ msg,
    const float* __restrict__ w_time, const float* __restrict__ b_time,
    const unsigned short* __restrict__ Web,
    const float* __restrict__ q, const float* __restrict__ k,
    const float* __restrict__ v,
    float* __restrict__ agg, float* __restrict__ denom)
{
    __shared__ short sWe[128][EA_LD];
    __shared__ __align__(16) char ubuf[ET * EP_LD * 4];
    short (*sEA)[EA_LD] = (short (*)[EA_LD])ubuf;
    float (*sEP)[EP_LD] = (float (*)[EP_LD])ubuf;
    __shared__ int s_src[ET], s_dst[ET];
    __shared__ float s_rel[ET];
    __shared__ float red[2][2][2];

    const int tid = threadIdx.x;
    const size_t e0 = (size_t)blockIdx.x * ET;

    {
        int r = tid >> 1, c0 = (tid & 1) * 64;
        const uint4* s = (const uint4*)(Web + r * 128 + c0);
        uint4* d = (uint4*)&sWe[r][c0];
#pragma unroll
        for (int i = 0; i < 8; i++) d[i] = s[i];
    }
    if (tid < ET) {
        size_t e = e0 + tid;
        int sn = ei[e];
        s_src[tid] = sn;
        s_dst[tid] = ei[N_EDGES + e];
        s_rel[tid] = fabsf(last_update[sn] - t[e]);
    }
    __syncthreads();

    {
        int j = tid >> 3, seg = tid & 7, k0 = seg * 16;
        size_t e = e0 + j;
        float vals[16];
        if (seg < 4) {
            const float4* mp = (const float4*)(msg + e * EDGEF + k0);
#pragma unroll
            for (int i = 0; i < 4; i++) {
                float4 a = mp[i];
                vals[4 * i] = a.x; vals[4 * i + 1] = a.y;
                vals[4 * i + 2] = a.z; vals[4 * i + 3] = a.w;
            }
        } else {
            int td = k0 - 64;
            float rel = s_rel[j];
#pragma unroll
            for (int i = 0; i < 16; i++)
                vals[i] = cosf(rel * w_time[td + i] + b_time[td + i]);
        }
        unsigned int* dp = (unsigned int*)&sEA[j][k0];
#pragma unroll
        for (int i = 0; i < 8; i++) {
            unsigned int lo = (unsigned short)f2bs(vals[2 * i]);
            unsigned int hi = (unsigned short)f2bs(vals[2 * i + 1]);
            dp[i] = lo | (hi << 16);
        }
    }
    __syncthreads();

    const int wave = tid >> 6, lane = tid & 63;
    const int quad = lane >> 4, l16 = lane & 15;
    const int mt = wave & 1, ntb = (wave >> 1) * 4;
    f32x4 acc[4];
#pragma unroll
    for (int i = 0; i < 4; i++) acc[i] = (f32x4){0.f, 0.f, 0.f, 0.f};
#pragma unroll
    for (int ko = 0; ko < 4; ko++) {
        bf16x8 a = *(const bf16x8*)&sEA[mt * 16 + l16][ko * 32 + quad * 8];
#pragma unroll
        for (int i = 0; i < 4; i++) {
            bf16x8 b = *(const bf16x8*)&sWe[(ntb + i) * 16 + l16][ko * 32 + quad * 8];
            acc[i] = __builtin_amdgcn_mfma_f32_16x16x32_bf16(a, b, acc[i], 0, 0, 0);
        }
    }
    __syncthreads();
#pragma unroll
    for (int i = 0; i < 4; i++)
#pragma unroll
        for (int r = 0; r < 4; r++)
            sEP[mt * 16 + quad * 4 + r][(ntb + i) * 16 + l16] = acc[i][r];
    __syncthreads();

    const int sub = tid >> 7, m = tid & 127;
    const int wv = (tid >> 6) & 1;
    for (int jj = 0; jj < ET / 2; jj++) {
        int j = jj * 2 + sub;
        int sn = s_src[j], dn = s_dst[j];
        float epv = sEP[j][m];
        float kk = k[(size_t)sn * MEM + m] + epv;
        float p = q[(size_t)dn * MEM + m] * kk;
        for (int off = 32; off > 0; off >>= 1) p += __shfl_down(p, off, 64);
        if (lane == 0) red[jj & 1][sub][wv] = p;
        __syncthreads();
        float ex = expf((red[jj & 1][sub][0] + red[jj & 1][sub][1]) * SCALE);
        float vv = v[(size_t)sn * MEM + m] + epv;
        atomicAdd(&agg[(size_t)dn * MEM + m], ex * vv);
        if (m == 0) atomicAdd(&denom[dn], ex);
    }
}

__global__ __launch_bounds__(128) void k_final(
    const float* __restrict__ h, const float* __restrict__ agg,
    const float* __restrict__ denom, const float* __restrict__ Abuf,
    const float* __restrict__ b_anti, float* __restrict__ out)
{
    __shared__ float hsh[NPB][MEM];
    const int m = threadIdx.x;
    const int n0 = blockIdx.x * NPB;
    for (int j = 0; j < NPB; j++) hsh[j][m] = h[(size_t)(n0 + j) * MEM + m];
    __syncthreads();
    float acc[NPB];
    float ba = b_anti[m];
    for (int j = 0; j < NPB; j++) {
        float dn = denom[n0 + j] + 1e-16f;
        acc[j] = ba + agg[(size_t)(n0 + j) * MEM + m] / dn;
    }
    const float4* A4 = (const float4*)(Abuf + (size_t)m * MEM);
    for (int d4 = 0; d4 < MEM / 4; d4++) {
        float4 w = A4[d4];
        int d = d4 * 4;
        for (int j = 0; j < NPB; j++)
            acc[j] += w.x * hsh[j][d] + w.y * hsh[j][d + 1] + w.z * hsh[j][d + 2] + w.w * hsh[j][d + 3];
    }
    for (int j = 0; j < NPB; j++) {
        float hv = hsh[j][m] + EPSILON * tanhf(acc[j]);
        out[(size_t)(n0 + j) * MEM + m] = tanhf(hv);
    }
}

extern "C" void kernel_launch(void* const* d_in, const int* in_sizes, int n_in,
                              void* d_out, int out_size, void* d_ws, size_t ws_size,
                              hipStream_t stream) {
    const float* x          = (const float*)d_in[0];
    const float* last_update= (const float*)d_in[1];
    const int*   ei         = (const int*)  d_in[2];
    const float* t          = (const float*)d_in[3];
    const float* msg        = (const float*)d_in[4];
    const float* w_time     = (const float*)d_in[5];
    const float* b_time     = (const float*)d_in[6];
    const float* W_enc      = (const float*)d_in[7];
    const float* b_enc      = (const float*)d_in[8];
    const float* Wq         = (const float*)d_in[9];
    const float* bq         = (const float*)d_in[10];
    const float* Wk         = (const float*)d_in[11];
    const float* bk         = (const float*)d_in[12];
    const float* Wv         = (const float*)d_in[13];
    const float* bv         = (const float*)d_in[14];
    const float* We         = (const float*)d_in[15];
    const float* W_anti     = (const float*)d_in[16];
    const float* b_anti     = (const float*)d_in[17];
    float* out = (float*)d_out;

    float* ws = (float*)d_ws;
    size_t nm = (size_t)N_NODES * MEM;
    float* h     = ws;                 // N*128
    float* q     = h + nm;             // N*128
    float* k     = q + nm;             // N*128
    float* v     = k + nm;             // N*128
    float* agg   = v + nm;             // N*128
    float* denom = agg + nm;           // N
    float* Abuf  = denom + N_NODES;    // 128*128 fp32
    unsigned short* Web   = (unsigned short*)(Abuf + MEM * MEM);  // 16384
    unsigned short* WencH = Web + 16384;    // 32768
    unsigned short* WencL = WencH + 32768;  // 32768
    unsigned short* Wqb   = WencL + 32768;  // 16384
    unsigned short* Wkb   = Wqb + 16384;    // 16384
    unsigned short* Wvb   = Wkb + 16384;    // 16384

    hipMemsetAsync(agg, 0, (nm + N_NODES) * sizeof(float), stream);
    k_prep<<<128, 256, 0, stream>>>(W_anti, We, W_enc, Wq, Wk, Wv,
                                    Abuf, Web, WencH, WencL, Wqb, Wkb, Wvb);

    k_node_proj<<<N_NODES / NT, 256, 0, stream>>>(
        x, b_enc, bq, bk, bv, WencH, WencL, Wqb, Wkb, Wvb, h, q, k, v);

    k_edge_all<<<N_EDGES / ET, 256, 0, stream>>>(
        ei, last_update, t, msg, w_time, b_time, Web, q, k, v, agg, denom);

    k_final<<<N_NODES / NPB, 128, 0, stream>>>(h, agg, denom, Abuf, b_anti, out);
}